// Round 9
// baseline (468.313 us; speedup 1.0000x reference)
//
#include <hip/hip_runtime.h>
#include <hip/hip_fp16.h>

#define EPS 0.01f
#define SCAN_BS 512
#define NCHUNKS 256
#define BUCKET_SHIFT 9
#define BUCKET_SZ (1 << BUCKET_SHIFT)
#define STAGE_CAP 16384

// ---------------- exclusive scan (3-kernel, n <= 512*512) ----------------

__global__ __launch_bounds__(SCAN_BS) void k_scan_block(const int* __restrict__ in,
                                                        int* __restrict__ out,
                                                        int* __restrict__ bsum, int n) {
    __shared__ int sd[SCAN_BS];
    int t = threadIdx.x;
    int gid = blockIdx.x * SCAN_BS + t;
    int v = (gid < n) ? in[gid] : 0;
    sd[t] = v;
    __syncthreads();
    for (int off = 1; off < SCAN_BS; off <<= 1) {
        int x = (t >= off) ? sd[t - off] : 0;
        __syncthreads();
        sd[t] += x;
        __syncthreads();
    }
    if (gid < n) out[gid] = sd[t] - v;  // exclusive
    if (t == SCAN_BS - 1) bsum[blockIdx.x] = sd[t];
}

__global__ __launch_bounds__(SCAN_BS) void k_scan_tops(int* __restrict__ bsum, int nb) {
    __shared__ int sd[SCAN_BS];
    int t = threadIdx.x;
    int v = (t < nb) ? bsum[t] : 0;
    sd[t] = v;
    __syncthreads();
    for (int off = 1; off < SCAN_BS; off <<= 1) {
        int x = (t >= off) ? sd[t - off] : 0;
        __syncthreads();
        sd[t] += x;
        __syncthreads();
    }
    if (t < nb) bsum[t] = sd[t] - v;  // exclusive
}

__global__ __launch_bounds__(SCAN_BS) void k_scan_add(int* __restrict__ out,
                                                      const int* __restrict__ bsum, int n) {
    int gid = blockIdx.x * SCAN_BS + threadIdx.x;
    if (gid < n) out[gid] += bsum[blockIdx.x];
}

// ---------------- bucketed edge sort ----------------

__global__ __launch_bounds__(256) void kA_bucket_hist(const int* __restrict__ dst,
                                                      int* __restrict__ bh, int e,
                                                      int nbuck, int ce) {
    extern __shared__ int hist[];  // nbuck
    int b = blockIdx.x, t = threadIdx.x;
    for (int i = t; i < nbuck; i += 256) hist[i] = 0;
    __syncthreads();
    int lo = b * ce, hi = min(lo + ce, e);
    for (int i = lo + t; i < hi; i += 256) atomicAdd(&hist[dst[i] >> BUCKET_SHIFT], 1);
    __syncthreads();
    for (int i = t; i < nbuck; i += 256) bh[i * NCHUNKS + b] = hist[i];  // [bucket][chunk]
}

__global__ __launch_bounds__(256) void kC_bucket_scatter(const int* __restrict__ src,
                                                         const int* __restrict__ dst,
                                                         const int* __restrict__ bhs,
                                                         unsigned int* __restrict__ eb, int e,
                                                         int nbuck, int ce) {
    extern __shared__ int cur[];  // nbuck
    int b = blockIdx.x, t = threadIdx.x;
    for (int i = t; i < nbuck; i += 256) cur[i] = bhs[i * NCHUNKS + b];
    __syncthreads();
    int lo = b * ce, hi = min(lo + ce, e);
    for (int i = lo + t; i < hi; i += 256) {
        int s = src[i], d = dst[i];
        int pos = atomicAdd(&cur[d >> BUCKET_SHIFT], 1);
        eb[pos] = ((unsigned int)(d & (BUCKET_SZ - 1)) << 23) | (unsigned int)s;
    }
}

// Fused: per-bucket edge stage (LDS) -> degree hist -> block scan ->
// degi/dinv/rowstart -> xs prescale -> csr fill. Block 0 zeroes partial.
__global__ __launch_bounds__(256) void kDeg_fill_prescale(const unsigned int* __restrict__ eb,
                                                          const int* __restrict__ bhs,
                                                          const float* __restrict__ x,
                                                          int* __restrict__ degi,
                                                          float* __restrict__ dinv,
                                                          int* __restrict__ rowstart,
                                                          int* __restrict__ csr_src,
                                                          __half* __restrict__ xs,
                                                          float* __restrict__ partial,
                                                          int n, int nbuck, int e) {
    __shared__ unsigned int ebs[STAGE_CAP];
    __shared__ int hist[BUCKET_SZ];  // later reused as csr cursors
    __shared__ int ps[256];
    __shared__ float dv[BUCKET_SZ];
    int k = blockIdx.x, t = threadIdx.x;
    if (k == 0 && t < 64) partial[t] = 0.f;
    for (int i = t; i < BUCKET_SZ; i += 256) hist[i] = 0;
    __syncthreads();
    int lo = bhs[k * NCHUNKS];
    int hi = (k + 1 < nbuck) ? bhs[(k + 1) * NCHUNKS] : e;
    int cnt = hi - lo;
    bool fits = (cnt <= STAGE_CAP);
    for (int i = t; i < cnt; i += 256) {
        unsigned int p = eb[lo + i];
        if (fits) ebs[i] = p;
        atomicAdd(&hist[p >> 23], 1);
    }
    __syncthreads();
    int a0 = hist[2 * t], a1 = hist[2 * t + 1];
    ps[t] = a0 + a1;
    __syncthreads();
    for (int off = 1; off < 256; off <<= 1) {
        int v = (t >= off) ? ps[t - off] : 0;
        __syncthreads();
        ps[t] += v;
        __syncthreads();
    }
    int excl = ps[t] - (a0 + a1);
    int node0 = k << BUCKET_SHIFT;
    int rs0 = lo + excl, rs1 = lo + excl + a0;
    {
        int nd0 = node0 + 2 * t, nd1 = nd0 + 1;
        float d0 = rsqrtf((float)a0 + 1.0f);
        float d1 = rsqrtf((float)a1 + 1.0f);
        dv[2 * t] = d0;
        dv[2 * t + 1] = d1;
        if (nd0 < n) {
            degi[nd0] = a0;
            dinv[nd0] = d0;
            rowstart[nd0] = rs0;
        }
        if (nd1 < n) {
            degi[nd1] = a1;
            dinv[nd1] = d1;
            rowstart[nd1] = rs1;
        }
    }
    __syncthreads();  // everyone has read a0/a1; reuse hist as cursors
    hist[2 * t] = rs0;
    hist[2 * t + 1] = rs1;
    // prescale: xs[node][c] = x[node][c] * dinv[node]
    for (int i = t; i < BUCKET_SZ * 16; i += 256) {
        int rl = i >> 4;
        int node = node0 + rl;
        if (node < n)
            xs[(size_t)node * 16 + (i & 15)] = __float2half(x[(size_t)node * 16 + (i & 15)] * dv[rl]);
    }
    __syncthreads();
    // csr fill from staged records
    for (int i = t; i < cnt; i += 256) {
        unsigned int p = fits ? ebs[i] : eb[lo + i];
        int dl = (int)(p >> 23);
        int s = (int)(p & 0x7fffffu);
        int pos = atomicAdd(&hist[dl], 1);
        csr_src[pos] = s;
    }
}

// ---------------- fused layer 1: gather16 (half2, 8 chunked slots) + MLP ----------------

__global__ __launch_bounds__(256) void k_l1_fused(const int* __restrict__ rowstart,
                                                  const int* __restrict__ degi,
                                                  const int* __restrict__ csr_src,
                                                  const float* __restrict__ dinv,
                                                  const __half* __restrict__ xs,
                                                  const float* __restrict__ W1,
                                                  const float* __restrict__ b1,
                                                  const float* __restrict__ W3,
                                                  __half* __restrict__ h2sA,
                                                  __half* __restrict__ h2sB, int n) {
    __shared__ float w1[16 * 64];
    __shared__ float w3[64 * 32];
    __shared__ float bs[64];
    __shared__ __align__(16) float a[16 * 16];
    __shared__ float z[16 * 64];
    int t = threadIdx.x;
    for (int i = t; i < 16 * 64; i += 256) w1[i] = W1[i];
    for (int i = t; i < 64 * 32; i += 256) w3[i] = W3[i];
    if (t < 64) bs[t] = b1[t];

    int row0 = blockIdx.x * 16;
    int wv = t >> 6;
    int lane = t & 63;
    int c2 = lane & 7;        // half2 column pair (cols 2c2, 2c2+1)
    int slot = lane >> 3;     // 0..7 edge slots (contiguous chunks)
    const __half2* xs2 = (const __half2*)xs;

    for (int nid = 0; nid < 4; ++nid) {
        int node = row0 + wv * 4 + nid;
        if (node < n) {
            const int* sp = csr_src + rowstart[node];
            int deg = degi[node];
            int L = (deg + 7) >> 3;
            int base = slot * L;
            int end = min(base + L, deg);
            float ax = 0.f, ay = 0.f, bx = 0.f, by = 0.f;
            int k = base;
            for (; k + 2 <= end; k += 2) {
                int s0 = sp[k], s1 = sp[k + 1];
                float2 v0 = __half22float2(xs2[(size_t)s0 * 8 + c2]);
                float2 v1 = __half22float2(xs2[(size_t)s1 * 8 + c2]);
                ax += v0.x; ay += v0.y;
                bx += v1.x; by += v1.y;
            }
            if (k < end) {
                int s0 = sp[k];
                float2 v0 = __half22float2(xs2[(size_t)s0 * 8 + c2]);
                ax += v0.x; ay += v0.y;
            }
            float sx = ax + bx, sy = ay + by;
            sx += __shfl_xor(sx, 8);  sy += __shfl_xor(sy, 8);
            sx += __shfl_xor(sx, 16); sy += __shfl_xor(sy, 16);
            sx += __shfl_xor(sx, 32); sy += __shfl_xor(sy, 32);
            if (slot == 0) {
                float2 self = __half22float2(xs2[(size_t)node * 8 + c2]);
                float dn = dinv[node];
                int r = wv * 4 + nid;
                ((float2*)(a + r * 16))[c2] = make_float2(dn * (sx + self.x), dn * (sy + self.y));
            }
        }
    }
    __syncthreads();

    // z = relu(a @ W1 + b1)
    for (int i = t; i < 1024; i += 256) {
        int r = i >> 6, c = i & 63;
        float acc = bs[c];
#pragma unroll
        for (int k = 0; k < 16; ++k) acc += a[r * 16 + k] * w1[k * 64 + c];
        z[i] = acc > 0.f ? acc : 0.f;
    }
    __syncthreads();
    // h2s{A,B} = (z @ W3) * dinv  (fp16, column-split)
    for (int i = t; i < 512; i += 256) {
        int r = i >> 5, c = i & 31;
        float acc = 0.f;
#pragma unroll
        for (int k = 0; k < 64; ++k) acc += z[r * 64 + k] * w3[k * 32 + c];
        int row = row0 + r;
        if (row < n) {
            __half hv = __float2half(acc * dinv[row]);
            if (c < 16) h2sA[(size_t)row * 16 + c] = hv;
            else        h2sB[(size_t)row * 16 + (c - 16)] = hv;
        }
    }
}

// ---------------- layer 2: edge-parallel, LDS accum, XCD-split column halves ------------
// One block per (bucket, half). blockIdx%8 in {0..3} -> half A (XCDs 0-3), {4..7} -> B.
// Stream the bucket's eb records; gather 32B row-half from L2-resident split array;
// accumulate into LDS acc[512][17] (pad 17 -> mixed-parity banks, ~2-way conflicts).

__global__ __launch_bounds__(256) void k_l2_edge_stats(const unsigned int* __restrict__ eb,
                                                       const int* __restrict__ bhs,
                                                       const __half* __restrict__ h2sA,
                                                       const __half* __restrict__ h2sB,
                                                       const float* __restrict__ dinv,
                                                       const float* __restrict__ b3,
                                                       float* __restrict__ out,
                                                       float* __restrict__ partial,
                                                       int n, int nbuck, int e) {
    __shared__ float acc[BUCKET_SZ][17];
    __shared__ float redS[16], redQ[16];
    int g = blockIdx.x;
    int half = (g >> 2) & 1;
    int k = (g >> 3) * 4 + (g & 3);
    if (k >= nbuck) return;
    const __half2* h2 = (const __half2*)(half ? h2sB : h2sA);
    int col0 = half << 4;
    int t = threadIdx.x;
    for (int i = t; i < BUCKET_SZ * 17; i += 256) ((float*)acc)[i] = 0.f;
    if (t < 16) { redS[t] = 0.f; redQ[t] = 0.f; }
    __syncthreads();

    int lo = bhs[k * NCHUNKS];
    int hi = (k + 1 < nbuck) ? bhs[(k + 1) * NCHUNKS] : e;
    int cnt = hi - lo;
    int lane = t & 63;
    int wv = t >> 6;
    int c2 = lane & 7;     // half2 pair within the 16-col half
    int slot = lane >> 3;  // 0..7 edges per wave-step

    int i = wv * 8 + slot;  // block stride = 4 waves * 8 slots = 32
    for (; i + 96 < cnt; i += 128) {
        unsigned int p0 = eb[lo + i];
        unsigned int p1 = eb[lo + i + 32];
        unsigned int p2 = eb[lo + i + 64];
        unsigned int p3 = eb[lo + i + 96];
        float2 v0 = __half22float2(h2[(size_t)(p0 & 0x7fffffu) * 8 + c2]);
        float2 v1 = __half22float2(h2[(size_t)(p1 & 0x7fffffu) * 8 + c2]);
        float2 v2 = __half22float2(h2[(size_t)(p2 & 0x7fffffu) * 8 + c2]);
        float2 v3 = __half22float2(h2[(size_t)(p3 & 0x7fffffu) * 8 + c2]);
        int d0 = p0 >> 23, d1 = p1 >> 23, d2 = p2 >> 23, d3 = p3 >> 23;
        atomicAdd(&acc[d0][2 * c2], v0.x);
        atomicAdd(&acc[d0][2 * c2 + 1], v0.y);
        atomicAdd(&acc[d1][2 * c2], v1.x);
        atomicAdd(&acc[d1][2 * c2 + 1], v1.y);
        atomicAdd(&acc[d2][2 * c2], v2.x);
        atomicAdd(&acc[d2][2 * c2 + 1], v2.y);
        atomicAdd(&acc[d3][2 * c2], v3.x);
        atomicAdd(&acc[d3][2 * c2 + 1], v3.y);
    }
    for (; i < cnt; i += 32) {
        unsigned int p = eb[lo + i];
        float2 v = __half22float2(h2[(size_t)(p & 0x7fffffu) * 8 + c2]);
        int d = p >> 23;
        atomicAdd(&acc[d][2 * c2], v.x);
        atomicAdd(&acc[d][2 * c2 + 1], v.y);
    }
    __syncthreads();

    // epilogue: out = dn*(acc + self) + bias, relu, stats
    int node0 = k << BUCKET_SHIFT;
    int c2p = t & 7;
    float2 bias = make_float2(b3[col0 + 2 * c2p], b3[col0 + 2 * c2p + 1]);
    float s_x = 0.f, s_y = 0.f, q_x = 0.f, q_y = 0.f;
    for (int d = t >> 3; d < BUCKET_SZ; d += 32) {
        int node = node0 + d;
        if (node >= n) break;
        float dn = dinv[node];
        float2 self = __half22float2(h2[(size_t)node * 8 + c2p]);
        float vx = dn * (acc[d][2 * c2p] + self.x) + bias.x;
        float vy = dn * (acc[d][2 * c2p + 1] + self.y) + bias.y;
        vx = vx > 0.f ? vx : 0.f;
        vy = vy > 0.f ? vy : 0.f;
        ((float2*)(out + (size_t)node * 32 + col0))[c2p] = make_float2(vx, vy);
        s_x += vx; s_y += vy;
        q_x += vx * vx; q_y += vy * vy;
    }
    atomicAdd(&redS[2 * c2p], s_x);
    atomicAdd(&redS[2 * c2p + 1], s_y);
    atomicAdd(&redQ[2 * c2p], q_x);
    atomicAdd(&redQ[2 * c2p + 1], q_y);
    __syncthreads();
    if (t < 16) {
        atomicAdd(&partial[col0 + t], redS[t]);
        atomicAdd(&partial[32 + col0 + t], redQ[t]);
    }
}

// ---------------- normalizer ----------------

__global__ void k_finalize(const float* __restrict__ partial, float* __restrict__ meaninv, int n) {
    int t = threadIdx.x;
    if (t < 32) {
        float invn = 1.0f / (float)n;
        float mean = partial[t] * invn;
        float var = partial[32 + t] * invn - mean * mean;
        var = var > EPS ? var : EPS;
        meaninv[t] = mean;
        meaninv[32 + t] = rsqrtf(var);
    }
}

__global__ void k_norm(float* __restrict__ h, const float* __restrict__ meaninv, int n) {
    long long idx = (long long)blockIdx.x * blockDim.x + threadIdx.x;
    if (idx < (long long)n * 32) {
        int c = (int)(idx & 31);
        h[idx] = (h[idx] - meaninv[c]) * meaninv[32 + c];
    }
}

extern "C" void kernel_launch(void* const* d_in, const int* in_sizes, int n_in,
                              void* d_out, int out_size, void* d_ws, size_t ws_size,
                              hipStream_t stream) {
    const float* x  = (const float*)d_in[0];
    const int* ei   = (const int*)d_in[1];
    const float* W1 = (const float*)d_in[2];
    const float* b1 = (const float*)d_in[3];
    const float* W3 = (const float*)d_in[4];
    const float* b3 = (const float*)d_in[5];

    const int N = in_sizes[0] / 16;
    const int E = in_sizes[1] / 2;
    const int* src = ei;       // edge_index[0]
    const int* dst = ei + E;   // edge_index[1]

    const int NBUCK = (N + BUCKET_SZ - 1) >> BUCKET_SHIFT;  // 196 for N=100000
    const int CE = (E + NCHUNKS - 1) / NCHUNKS;
    const int BH_TOTAL = NBUCK * NCHUNKS;

    char* ws = (char*)d_ws;
    int*   degi     = (int*)ws;          ws += (size_t)N * 4;
    float* dinv     = (float*)ws;        ws += (size_t)N * 4;
    int*   rowstart = (int*)ws;          ws += (size_t)N * 4;
    int*   bsum2    = (int*)ws;          ws += (size_t)SCAN_BS * 4;
    int*   bh       = (int*)ws;          ws += (size_t)BH_TOTAL * 4;
    int*   bhs      = (int*)ws;          ws += (size_t)BH_TOTAL * 4;
    unsigned int* eb = (unsigned int*)ws; ws += (size_t)E * 4;
    int*   csr_src  = (int*)ws;          ws += (size_t)E * 4;
    __half* xs      = (__half*)ws;       ws += (size_t)N * 16 * 2;
    __half* h2sA    = (__half*)ws;       ws += (size_t)N * 16 * 2;
    __half* h2sB    = (__half*)ws;       ws += (size_t)N * 16 * 2;
    float* partial  = (float*)ws;        ws += 64 * 4;
    float* meaninv  = (float*)ws;

    float* out = (float*)d_out;  // N*32

    const int NB2 = (BH_TOTAL + SCAN_BS - 1) / SCAN_BS;

    // bucketed edge sort
    kA_bucket_hist<<<NCHUNKS, 256, NBUCK * 4, stream>>>(dst, bh, E, NBUCK, CE);
    k_scan_block<<<NB2, SCAN_BS, 0, stream>>>(bh, bhs, bsum2, BH_TOTAL);
    k_scan_tops<<<1, SCAN_BS, 0, stream>>>(bsum2, NB2);
    k_scan_add<<<NB2, SCAN_BS, 0, stream>>>(bhs, bsum2, BH_TOTAL);
    kC_bucket_scatter<<<NCHUNKS, 256, NBUCK * 4, stream>>>(src, dst, bhs, eb, E, NBUCK, CE);

    // fused: stage bucket edges in LDS -> hist -> scan -> degi/dinv/rowstart
    //        -> xs prescale -> csr fill (+ partial zero)
    kDeg_fill_prescale<<<NBUCK, 256, 0, stream>>>(eb, bhs, x, degi, dinv, rowstart,
                                                  csr_src, xs, partial, N, NBUCK, E);

    // layer 1: fused gather + MLP (writes column-split fp16 h2sA/h2sB)
    k_l1_fused<<<(N + 15) / 16, 256, 0, stream>>>(rowstart, degi, csr_src, dinv, xs,
                                                  W1, b1, W3, h2sA, h2sB, N);

    // layer 2: edge-parallel LDS-accum gather + bias + relu + stats
    const int G2 = ((NBUCK + 3) / 4) * 8;
    k_l2_edge_stats<<<G2, 256, 0, stream>>>(eb, bhs, h2sA, h2sB, dinv, b3, out, partial,
                                            N, NBUCK, E);

    // normalizer
    k_finalize<<<1, 64, 0, stream>>>(partial, meaninv, N);
    k_norm<<<((long long)N * 32 + 255) / 256, 256, 0, stream>>>(out, meaninv, N);
}

// Round 10
// 191.686 us; speedup vs baseline: 2.4431x; 2.4431x over previous
//
#include <hip/hip_runtime.h>
#include <hip/hip_fp16.h>

#define EPS 0.01f
#define SCAN_BS 512
#define NCHUNKS 256
#define BUCKET_SHIFT 9
#define BUCKET_SZ (1 << BUCKET_SHIFT)
#define STAGE_CAP 16384

// ---------------- exclusive scan (3-kernel, n <= 512*512) ----------------

__global__ __launch_bounds__(SCAN_BS) void k_scan_block(const int* __restrict__ in,
                                                        int* __restrict__ out,
                                                        int* __restrict__ bsum, int n) {
    __shared__ int sd[SCAN_BS];
    int t = threadIdx.x;
    int gid = blockIdx.x * SCAN_BS + t;
    int v = (gid < n) ? in[gid] : 0;
    sd[t] = v;
    __syncthreads();
    for (int off = 1; off < SCAN_BS; off <<= 1) {
        int x = (t >= off) ? sd[t - off] : 0;
        __syncthreads();
        sd[t] += x;
        __syncthreads();
    }
    if (gid < n) out[gid] = sd[t] - v;  // exclusive
    if (t == SCAN_BS - 1) bsum[blockIdx.x] = sd[t];
}

__global__ __launch_bounds__(SCAN_BS) void k_scan_tops(int* __restrict__ bsum, int nb) {
    __shared__ int sd[SCAN_BS];
    int t = threadIdx.x;
    int v = (t < nb) ? bsum[t] : 0;
    sd[t] = v;
    __syncthreads();
    for (int off = 1; off < SCAN_BS; off <<= 1) {
        int x = (t >= off) ? sd[t - off] : 0;
        __syncthreads();
        sd[t] += x;
        __syncthreads();
    }
    if (t < nb) bsum[t] = sd[t] - v;  // exclusive
}

__global__ __launch_bounds__(SCAN_BS) void k_scan_add(int* __restrict__ out,
                                                      const int* __restrict__ bsum, int n) {
    int gid = blockIdx.x * SCAN_BS + threadIdx.x;
    if (gid < n) out[gid] += bsum[blockIdx.x];
}

// ---------------- bucketed edge sort ----------------

__global__ __launch_bounds__(256) void kA_bucket_hist(const int* __restrict__ dst,
                                                      int* __restrict__ bh, int e,
                                                      int nbuck, int ce) {
    extern __shared__ int hist[];  // nbuck
    int b = blockIdx.x, t = threadIdx.x;
    for (int i = t; i < nbuck; i += 256) hist[i] = 0;
    __syncthreads();
    int lo = b * ce, hi = min(lo + ce, e);
    for (int i = lo + t; i < hi; i += 256) atomicAdd(&hist[dst[i] >> BUCKET_SHIFT], 1);
    __syncthreads();
    for (int i = t; i < nbuck; i += 256) bh[i * NCHUNKS + b] = hist[i];  // [bucket][chunk]
}

__global__ __launch_bounds__(256) void kC_bucket_scatter(const int* __restrict__ src,
                                                         const int* __restrict__ dst,
                                                         const int* __restrict__ bhs,
                                                         unsigned int* __restrict__ eb, int e,
                                                         int nbuck, int ce) {
    extern __shared__ int cur[];  // nbuck
    int b = blockIdx.x, t = threadIdx.x;
    for (int i = t; i < nbuck; i += 256) cur[i] = bhs[i * NCHUNKS + b];
    __syncthreads();
    int lo = b * ce, hi = min(lo + ce, e);
    for (int i = lo + t; i < hi; i += 256) {
        int s = src[i], d = dst[i];
        int pos = atomicAdd(&cur[d >> BUCKET_SHIFT], 1);
        eb[pos] = ((unsigned int)(d & (BUCKET_SZ - 1)) << 23) | (unsigned int)s;
    }
}

// Fused: per-bucket edge stage (LDS) -> degree hist -> block scan ->
// degi/dinv/rowstart -> xs prescale -> csr fill. Block 0 zeroes partial.
__global__ __launch_bounds__(256) void kDeg_fill_prescale(const unsigned int* __restrict__ eb,
                                                          const int* __restrict__ bhs,
                                                          const float* __restrict__ x,
                                                          int* __restrict__ degi,
                                                          float* __restrict__ dinv,
                                                          int* __restrict__ rowstart,
                                                          int* __restrict__ csr_src,
                                                          __half* __restrict__ xs,
                                                          float* __restrict__ partial,
                                                          int n, int nbuck, int e) {
    __shared__ unsigned int ebs[STAGE_CAP];
    __shared__ int hist[BUCKET_SZ];  // later reused as csr cursors
    __shared__ int ps[256];
    __shared__ float dv[BUCKET_SZ];
    int k = blockIdx.x, t = threadIdx.x;
    if (k == 0 && t < 64) partial[t] = 0.f;
    for (int i = t; i < BUCKET_SZ; i += 256) hist[i] = 0;
    __syncthreads();
    int lo = bhs[k * NCHUNKS];
    int hi = (k + 1 < nbuck) ? bhs[(k + 1) * NCHUNKS] : e;
    int cnt = hi - lo;
    bool fits = (cnt <= STAGE_CAP);
    for (int i = t; i < cnt; i += 256) {
        unsigned int p = eb[lo + i];
        if (fits) ebs[i] = p;
        atomicAdd(&hist[p >> 23], 1);
    }
    __syncthreads();
    int a0 = hist[2 * t], a1 = hist[2 * t + 1];
    ps[t] = a0 + a1;
    __syncthreads();
    for (int off = 1; off < 256; off <<= 1) {
        int v = (t >= off) ? ps[t - off] : 0;
        __syncthreads();
        ps[t] += v;
        __syncthreads();
    }
    int excl = ps[t] - (a0 + a1);
    int node0 = k << BUCKET_SHIFT;
    int rs0 = lo + excl, rs1 = lo + excl + a0;
    {
        int nd0 = node0 + 2 * t, nd1 = nd0 + 1;
        float d0 = rsqrtf((float)a0 + 1.0f);
        float d1 = rsqrtf((float)a1 + 1.0f);
        dv[2 * t] = d0;
        dv[2 * t + 1] = d1;
        if (nd0 < n) {
            degi[nd0] = a0;
            dinv[nd0] = d0;
            rowstart[nd0] = rs0;
        }
        if (nd1 < n) {
            degi[nd1] = a1;
            dinv[nd1] = d1;
            rowstart[nd1] = rs1;
        }
    }
    __syncthreads();  // everyone has read a0/a1; reuse hist as cursors
    hist[2 * t] = rs0;
    hist[2 * t + 1] = rs1;
    // prescale: xs[node][c] = x[node][c] * dinv[node]  (half2 vectorized)
    {
        const float2* xf2 = (const float2*)x;
        __half2* xs2 = (__half2*)xs;
        for (int i = t; i < BUCKET_SZ * 8; i += 256) {
            int rl = i >> 3;
            int node = node0 + rl;
            if (node < n) {
                float2 vv = xf2[(size_t)node * 8 + (i & 7)];
                float d = dv[rl];
                xs2[(size_t)node * 8 + (i & 7)] = __floats2half2_rn(vv.x * d, vv.y * d);
            }
        }
    }
    __syncthreads();
    // csr fill from staged records
    for (int i = t; i < cnt; i += 256) {
        unsigned int p = fits ? ebs[i] : eb[lo + i];
        int dl = (int)(p >> 23);
        int s = (int)(p & 0x7fffffu);
        int pos = atomicAdd(&hist[dl], 1);
        csr_src[pos] = s;
    }
}

// ---------------- fused layer 1: gather16 (8B/lane, pk-fp16, 16 slots) + MLP ------------
// block = 256 threads = 4 waves; 16 nodes per block (4 per wave).

__global__ __launch_bounds__(256) void k_l1_fused(const int* __restrict__ rowstart,
                                                  const int* __restrict__ degi,
                                                  const int* __restrict__ csr_src,
                                                  const float* __restrict__ dinv,
                                                  const __half* __restrict__ xs,
                                                  const float* __restrict__ W1,
                                                  const float* __restrict__ b1,
                                                  const float* __restrict__ W3,
                                                  __half* __restrict__ h2sA,
                                                  __half* __restrict__ h2sB, int n) {
    __shared__ float w1[16 * 64];
    __shared__ float w3[64 * 32];
    __shared__ float bs[64];
    __shared__ __align__(16) float a[16 * 16];
    __shared__ float z[16 * 64];
    int t = threadIdx.x;
    for (int i = t; i < 16 * 64; i += 256) w1[i] = W1[i];
    for (int i = t; i < 64 * 32; i += 256) w3[i] = W3[i];
    if (t < 64) bs[t] = b1[t];

    int row0 = blockIdx.x * 16;
    int wv = t >> 6;
    int lane = t & 63;
    int c2 = lane & 3;     // quarter: halfs 4c2..4c2+3 of the 16-col row
    int slot = lane >> 2;  // 0..15 edge slots (contiguous chunks)
    const float2* xf2 = (const float2*)xs;

    for (int nid = 0; nid < 4; ++nid) {
        int node = row0 + wv * 4 + nid;
        if (node < n) {
            const int* sp = csr_src + rowstart[node];
            int deg = degi[node];
            int L = (deg + 15) >> 4;
            int base = slot * L;
            int end = min(base + L, deg);
            __half2 acc0 = __float2half2_rn(0.f), acc1 = acc0;
            for (int k = base; k < end; ++k) {
                int s0 = sp[k];
                float2 raw = xf2[(size_t)s0 * 4 + c2];
                acc0 = __hadd2(acc0, *(const __half2*)&raw.x);
                acc1 = __hadd2(acc1, *(const __half2*)&raw.y);
            }
#pragma unroll
            for (int m = 4; m <= 32; m <<= 1) {
                float o0 = __shfl_xor(*(float*)&acc0, m);
                float o1 = __shfl_xor(*(float*)&acc1, m);
                acc0 = __hadd2(acc0, *(__half2*)&o0);
                acc1 = __hadd2(acc1, *(__half2*)&o1);
            }
            if (slot == 0) {
                float2 lo = __half22float2(acc0), hi = __half22float2(acc1);
                float2 sraw = xf2[(size_t)node * 4 + c2];
                float2 slo = __half22float2(*(const __half2*)&sraw.x);
                float2 shi = __half22float2(*(const __half2*)&sraw.y);
                float dn = dinv[node];
                int r = wv * 4 + nid;
                float4 res;
                res.x = dn * (lo.x + slo.x);
                res.y = dn * (lo.y + slo.y);
                res.z = dn * (hi.x + shi.x);
                res.w = dn * (hi.y + shi.y);
                ((float4*)(a + r * 16))[c2] = res;
            }
        }
    }
    __syncthreads();

    // z = relu(a @ W1 + b1)
    for (int i = t; i < 1024; i += 256) {
        int r = i >> 6, c = i & 63;
        float acc = bs[c];
#pragma unroll
        for (int k = 0; k < 16; ++k) acc += a[r * 16 + k] * w1[k * 64 + c];
        z[i] = acc > 0.f ? acc : 0.f;
    }
    __syncthreads();
    // h2s{A,B} = (z @ W3) * dinv  (fp16, column-split)
    for (int i = t; i < 512; i += 256) {
        int r = i >> 5, c = i & 31;
        float acc = 0.f;
#pragma unroll
        for (int k = 0; k < 64; ++k) acc += z[r * 64 + k] * w3[k * 32 + c];
        int row = row0 + r;
        if (row < n) {
            __half hv = __float2half(acc * dinv[row]);
            if (c < 16) h2sA[(size_t)row * 16 + c] = hv;
            else        h2sB[(size_t)row * 16 + (c - 16)] = hv;
        }
    }
}

// ---------------- layer 2 gather: XCD-split halves, 8B/lane, pk-fp16, 16 slots ----------
// blockIdx%8 in {0..3} -> half A (XCDs 0-3), {4..7} -> half B (XCDs 4-7).

__global__ __launch_bounds__(256) void k_gather16x2_stats(const int* __restrict__ rowstart,
                                                          const int* __restrict__ degi,
                                                          const int* __restrict__ csr_src,
                                                          const float* __restrict__ dinv,
                                                          const __half* __restrict__ h2sA,
                                                          const __half* __restrict__ h2sB,
                                                          const float* __restrict__ b3,
                                                          float* __restrict__ out,
                                                          float* __restrict__ partial, int n) {
    int g = blockIdx.x;
    int half = (g >> 2) & 1;
    int nblk = (g >> 3) * 4 + (g & 3);
    int M = (n + 31) >> 5;
    if (nblk >= M) return;
    const float2* h2f = (const float2*)(half ? h2sB : h2sA);
    int col0 = half << 4;
    int t = threadIdx.x;
    int lane = t & 63;
    int c2 = lane & 3;     // quarter: cols col0+4c2..col0+4c2+3
    int slot = lane >> 2;  // 0..15 (contiguous chunks)
    int wv = t >> 6;
    float4 bias = ((const float4*)(b3 + col0))[c2];
    float4 sacc = make_float4(0.f, 0.f, 0.f, 0.f);
    float4 qacc = make_float4(0.f, 0.f, 0.f, 0.f);
    for (int it = 0; it < 8; ++it) {
        int node = nblk * 32 + it * 4 + wv;
        if (node < n) {
            const int* sp = csr_src + rowstart[node];
            int deg = degi[node];
            int L = (deg + 15) >> 4;
            int base = slot * L;
            int end = min(base + L, deg);
            __half2 acc0 = __float2half2_rn(0.f), acc1 = acc0;
            for (int k = base; k < end; ++k) {
                int s0 = sp[k];
                float2 raw = h2f[(size_t)s0 * 4 + c2];
                acc0 = __hadd2(acc0, *(const __half2*)&raw.x);
                acc1 = __hadd2(acc1, *(const __half2*)&raw.y);
            }
#pragma unroll
            for (int m = 4; m <= 32; m <<= 1) {
                float o0 = __shfl_xor(*(float*)&acc0, m);
                float o1 = __shfl_xor(*(float*)&acc1, m);
                acc0 = __hadd2(acc0, *(__half2*)&o0);
                acc1 = __hadd2(acc1, *(__half2*)&o1);
            }
            if (slot == 0) {
                float2 lo = __half22float2(acc0), hi = __half22float2(acc1);
                float2 sraw = h2f[(size_t)node * 4 + c2];
                float2 slo = __half22float2(*(const __half2*)&sraw.x);
                float2 shi = __half22float2(*(const __half2*)&sraw.y);
                float dn = dinv[node];
                float4 v;
                v.x = dn * (lo.x + slo.x) + bias.x;
                v.y = dn * (lo.y + slo.y) + bias.y;
                v.z = dn * (hi.x + shi.x) + bias.z;
                v.w = dn * (hi.y + shi.y) + bias.w;
                v.x = fmaxf(v.x, 0.f);
                v.y = fmaxf(v.y, 0.f);
                v.z = fmaxf(v.z, 0.f);
                v.w = fmaxf(v.w, 0.f);
                ((float4*)(out + (size_t)node * 32 + col0))[c2] = v;
                sacc.x += v.x; sacc.y += v.y; sacc.z += v.z; sacc.w += v.w;
                qacc.x += v.x * v.x; qacc.y += v.y * v.y;
                qacc.z += v.z * v.z; qacc.w += v.w * v.w;
            }
        }
    }
    __shared__ __align__(16) float ls[64], lq[64];
    if (slot == 0) {
        ((float4*)ls)[wv * 4 + c2] = sacc;
        ((float4*)lq)[wv * 4 + c2] = qacc;
    }
    __syncthreads();
    if (t < 16) {
        float a = 0.f, b = 0.f;
#pragma unroll
        for (int w = 0; w < 4; ++w) {
            a += ls[w * 16 + t];
            b += lq[w * 16 + t];
        }
        atomicAdd(&partial[col0 + t], a);
        atomicAdd(&partial[32 + col0 + t], b);
    }
}

// ---------------- normalizer ----------------

__global__ void k_finalize(const float* __restrict__ partial, float* __restrict__ meaninv, int n) {
    int t = threadIdx.x;
    if (t < 32) {
        float invn = 1.0f / (float)n;
        float mean = partial[t] * invn;
        float var = partial[32 + t] * invn - mean * mean;
        var = var > EPS ? var : EPS;
        meaninv[t] = mean;
        meaninv[32 + t] = rsqrtf(var);
    }
}

__global__ void k_norm(float* __restrict__ h, const float* __restrict__ meaninv, int n) {
    int idx = blockIdx.x * blockDim.x + threadIdx.x;  // over N*8 float4s
    if (idx < n * 8) {
        int c4 = idx & 7;
        float4 v = ((float4*)h)[idx];
        float4 m = ((const float4*)meaninv)[c4];
        float4 iv = ((const float4*)(meaninv + 32))[c4];
        v.x = (v.x - m.x) * iv.x;
        v.y = (v.y - m.y) * iv.y;
        v.z = (v.z - m.z) * iv.z;
        v.w = (v.w - m.w) * iv.w;
        ((float4*)h)[idx] = v;
    }
}

extern "C" void kernel_launch(void* const* d_in, const int* in_sizes, int n_in,
                              void* d_out, int out_size, void* d_ws, size_t ws_size,
                              hipStream_t stream) {
    const float* x  = (const float*)d_in[0];
    const int* ei   = (const int*)d_in[1];
    const float* W1 = (const float*)d_in[2];
    const float* b1 = (const float*)d_in[3];
    const float* W3 = (const float*)d_in[4];
    const float* b3 = (const float*)d_in[5];

    const int N = in_sizes[0] / 16;
    const int E = in_sizes[1] / 2;
    const int* src = ei;       // edge_index[0]
    const int* dst = ei + E;   // edge_index[1]

    const int NBUCK = (N + BUCKET_SZ - 1) >> BUCKET_SHIFT;  // 196 for N=100000
    const int CE = (E + NCHUNKS - 1) / NCHUNKS;
    const int BH_TOTAL = NBUCK * NCHUNKS;

    char* ws = (char*)d_ws;
    int*   degi     = (int*)ws;          ws += (size_t)N * 4;
    float* dinv     = (float*)ws;        ws += (size_t)N * 4;
    int*   rowstart = (int*)ws;          ws += (size_t)N * 4;
    int*   bsum2    = (int*)ws;          ws += (size_t)SCAN_BS * 4;
    int*   bh       = (int*)ws;          ws += (size_t)BH_TOTAL * 4;
    int*   bhs      = (int*)ws;          ws += (size_t)BH_TOTAL * 4;
    unsigned int* eb = (unsigned int*)ws; ws += (size_t)E * 4;
    int*   csr_src  = (int*)ws;          ws += (size_t)E * 4;
    __half* xs      = (__half*)ws;       ws += (size_t)N * 16 * 2;
    __half* h2sA    = (__half*)ws;       ws += (size_t)N * 16 * 2;
    __half* h2sB    = (__half*)ws;       ws += (size_t)N * 16 * 2;
    float* partial  = (float*)ws;        ws += 64 * 4;
    float* meaninv  = (float*)ws;

    float* out = (float*)d_out;  // N*32

    const int NB2 = (BH_TOTAL + SCAN_BS - 1) / SCAN_BS;

    // bucketed edge sort
    kA_bucket_hist<<<NCHUNKS, 256, NBUCK * 4, stream>>>(dst, bh, E, NBUCK, CE);
    k_scan_block<<<NB2, SCAN_BS, 0, stream>>>(bh, bhs, bsum2, BH_TOTAL);
    k_scan_tops<<<1, SCAN_BS, 0, stream>>>(bsum2, NB2);
    k_scan_add<<<NB2, SCAN_BS, 0, stream>>>(bhs, bsum2, BH_TOTAL);
    kC_bucket_scatter<<<NCHUNKS, 256, NBUCK * 4, stream>>>(src, dst, bhs, eb, E, NBUCK, CE);

    // fused: stage bucket edges in LDS -> hist -> scan -> degi/dinv/rowstart
    //        -> xs prescale -> csr fill (+ partial zero)
    kDeg_fill_prescale<<<NBUCK, 256, 0, stream>>>(eb, bhs, x, degi, dinv, rowstart,
                                                  csr_src, xs, partial, N, NBUCK, E);

    // layer 1: fused gather + MLP (writes column-split fp16 h2sA/h2sB)
    k_l1_fused<<<(N + 15) / 16, 256, 0, stream>>>(rowstart, degi, csr_src, dinv, xs,
                                                  W1, b1, W3, h2sA, h2sB, N);

    // layer 2: XCD-split gather + bias + relu + stats
    const int M = (N + 31) >> 5;
    const int G = ((M + 3) / 4) * 8;
    k_gather16x2_stats<<<G, 256, 0, stream>>>(rowstart, degi, csr_src, dinv, h2sA, h2sB,
                                              b3, out, partial, N);

    // normalizer
    k_finalize<<<1, 64, 0, stream>>>(partial, meaninv, N);
    k_norm<<<(N * 8 + 255) / 256, 256, 0, stream>>>(out, meaninv, N);
}